// Round 1
// baseline (574.152 us; speedup 1.0000x reference)
//
#include <hip/hip_runtime.h>

#define H 1024
#define W 1024
#define NIMG 8
#define CPT 4                   // columns per thread
#define TH 8                    // output rows per wave-tile (halved: 2x grid)
#define NBX 4                   // x-quadrants: 64 lanes * 4 cols * 4 = 1024
#define WPB 4                   // waves per block, stacked in y
#define NBY (H / (TH * WPB))    // 32
#define NBLK (NBX * NBY * NIMG) // 1024 blocks = 4 blocks/CU = 16 waves/CU
#define NWAVES (NBLK * WPB)     // 4096
#define EPS 1e-5f

struct RS { float I[CPT], J[CPT], II[CPT], JJ[CPT], IJ[CPT]; };
// One row's raw pixels for a 4-col strip: 12 I-px + 12 J-px (3 float4 each)
struct Px { float4 aL, aC, aR, bL, bC, bR; };

// Pure load phase: issue 6 float4 loads (edge-guarded), no dependent compute.
__device__ __forceinline__ Px load_px(const float* __restrict__ Ip,
                                      const float* __restrict__ Jp,
                                      int r, int X, bool okL, bool okR) {
  Px p;
  const float4 z = make_float4(0.f, 0.f, 0.f, 0.f);
  p.aL = z; p.aC = z; p.aR = z; p.bL = z; p.bC = z; p.bR = z;
  if ((unsigned)r < (unsigned)H) {          // wave-uniform row guard
    const float* Irow = Ip + (size_t)r * W;
    const float* Jrow = Jp + (size_t)r * W;
    p.aC = *reinterpret_cast<const float4*>(Irow + X);
    p.bC = *reinterpret_cast<const float4*>(Jrow + X);
    if (okL) {
      p.aL = *reinterpret_cast<const float4*>(Irow + X - 4);
      p.bL = *reinterpret_cast<const float4*>(Jrow + X - 4);
    }
    if (okR) {
      p.aR = *reinterpret_cast<const float4*>(Irow + X + 4);
      p.bR = *reinterpret_cast<const float4*>(Jrow + X + 4);
    }
  }
  return p;
}

// Pure compute phase: horizontal 9-box rowsums for 4 output cols from registers.
__device__ __forceinline__ void compute_rs(const Px& p, RS& o) {
  const float a[12] = {p.aL.x, p.aL.y, p.aL.z, p.aL.w,
                       p.aC.x, p.aC.y, p.aC.z, p.aC.w,
                       p.aR.x, p.aR.y, p.aR.z, p.aR.w};
  const float b[12] = {p.bL.x, p.bL.y, p.bL.z, p.bL.w,
                       p.bC.x, p.bC.y, p.bC.z, p.bC.w,
                       p.bR.x, p.bR.y, p.bR.z, p.bR.w};
  float sI = 0.f, sJ = 0.f, sII = 0.f, sJJ = 0.f, sIJ = 0.f;
  #pragma unroll
  for (int k = 0; k < 9; ++k) {
    sI += a[k]; sJ += b[k];
    sII = fmaf(a[k], a[k], sII);
    sJJ = fmaf(b[k], b[k], sJJ);
    sIJ = fmaf(a[k], b[k], sIJ);
  }
  o.I[0] = sI; o.J[0] = sJ; o.II[0] = sII; o.JJ[0] = sJJ; o.IJ[0] = sIJ;
  #pragma unroll
  for (int i = 1; i < CPT; ++i) {
    float an = a[i + 8], al = a[i - 1], bn = b[i + 8], bl = b[i - 1];
    sI += an - al;  sJ += bn - bl;
    sII = fmaf(-al, al, fmaf(an, an, sII));
    sJJ = fmaf(-bl, bl, fmaf(bn, bn, sJJ));
    sIJ = fmaf(-al, bl, fmaf(an, bn, sIJ));
    o.I[i] = sI; o.J[i] = sJ; o.II[i] = sII; o.JJ[i] = sJJ; o.IJ[i] = sIJ;
  }
}

// No LDS, no barriers. Each wave walks a 256-col x 8-row tile; each thread a
// 4-col strip with vertical running window sums in registers. Software
// pipeline depth 1: next row's 6 float4 loads are issued before the current
// row's rowsum compute consumes its registers.
__global__ __launch_bounds__(256, 4)
void ncc_main(const float* __restrict__ I, const float* __restrict__ J,
              float* __restrict__ partial) {
  const int tid  = threadIdx.x;
  const int lane = tid & 63, wv = tid >> 6;
  // XCD-bijective remap (NBLK = 1024 = 8 * 128): XCD k (= bid % 8) processes
  // contiguous tiles [k*128, (k+1)*128) == exactly image k -> vertical-halo
  // re-reads stay inside one XCD's L2 instead of re-fetching cross-XCD.
  const int bid  = (int)blockIdx.x;
  const int tile = ((bid & 7) << 7) | (bid >> 3);
  const int bx   = tile & (NBX - 1);
  const int rest = tile / NBX;            // [0, 256)
  const int by   = rest & (NBY - 1);
  const int bz   = rest / NBY;            // image index
  const int X  = bx * 256 + lane * CPT;
  const int y0 = (by * WPB + wv) * TH;
  const bool okL = (X >= 4);
  const bool okR = (X + 8 <= W);
  const size_t img_off = (size_t)bz * H * W;
  const float* Ip = I + img_off;
  const float* Jp = J + img_off;

  float wI[CPT], wJ[CPT], wII[CPT], wJJ[CPT], wIJ[CPT];
  #pragma unroll
  for (int i = 0; i < CPT; ++i) { wI[i]=wJ[i]=wII[i]=wJJ[i]=wIJ[i]=0.f; }
  float acc = 0.f;
  const float inv81 = 1.0f / 81.0f;

  auto wadd = [&](const RS& o) {
    #pragma unroll
    for (int i = 0; i < CPT; ++i) {
      wI[i]  += o.I[i];  wJ[i]  += o.J[i];
      wII[i] += o.II[i]; wJJ[i] += o.JJ[i]; wIJ[i] += o.IJ[i];
    }
  };
  auto wsub = [&](const RS& o) {
    #pragma unroll
    for (int i = 0; i < CPT; ++i) {
      wI[i]  -= o.I[i];  wJ[i]  -= o.J[i];
      wII[i] -= o.II[i]; wJJ[i] -= o.JJ[i]; wIJ[i] -= o.IJ[i];
    }
  };
  auto emit = [&]() {
    #pragma unroll
    for (int i = 0; i < CPT; ++i) {
      float cross = fmaf(-(wI[i] * wJ[i]), inv81, wIJ[i]);
      float Iv    = fmaf(-(wI[i] * wI[i]), inv81, wII[i]);
      float Jv    = fmaf(-(wJ[i] * wJ[i]), inv81, wJJ[i]);
      acc = fmaf(cross * cross,
                 __builtin_amdgcn_rcpf(fmaf(Iv, Jv, EPS)), acc);
    }
  };

  // ---- software-pipelined vertical walk ----
  // warm-up: add rows y0-4 .. y0+3 (always one load in flight ahead)
  Px cur = load_px(Ip, Jp, y0 - 4, X, okL, okR);
  #pragma unroll
  for (int i = 0; i < 8; ++i) {
    Px nxt = load_px(Ip, Jp, y0 - 3 + i, X, okL, okR);
    RS o; compute_rs(cur, o); wadd(o);
    cur = nxt;
  }
  // cur = row y0+4: first output row, prefetch first leaving row (L2-hot)
  {
    Px nxt = load_px(Ip, Jp, y0 - 4, X, okL, okR);
    RS o; compute_rs(cur, o); wadd(o); emit();
    cur = nxt;
  }
  // steady state: cur alternates {leaving row, entering row}, next load
  // always issued before the current compute.
  #pragma unroll
  for (int k = 0; k < TH - 1; ++k) {
    Px nadd = load_px(Ip, Jp, y0 + 5 + k, X, okL, okR);   // fresh row (HBM/L3)
    RS o; compute_rs(cur, o); wsub(o);                    // cur = row y0-4+k
    cur = nadd;
    Px nsub = (k < TH - 2) ? load_px(Ip, Jp, y0 - 3 + k, X, okL, okR) : cur;
    RS o2; compute_rs(cur, o2); wadd(o2); emit();
    cur = nsub;
  }

  // wave reduction -> one partial per wave (no LDS, no barrier)
  #pragma unroll
  for (int off = 32; off > 0; off >>= 1)
    acc += __shfl_down(acc, off, 64);
  if (lane == 0)
    partial[tile * WPB + wv] = acc;
}

__global__ __launch_bounds__(256)
void ncc_reduce(const float* __restrict__ partial, float* __restrict__ out) {
  __shared__ float red[4];
  const int tid = threadIdx.x;
  const float4* p4 = reinterpret_cast<const float4*>(partial);
  float s = 0.f;
  #pragma unroll
  for (int i = tid; i < NWAVES / 4; i += 256) {
    float4 v = p4[i];
    s += (v.x + v.y) + (v.z + v.w);
  }
  #pragma unroll
  for (int off = 32; off > 0; off >>= 1)
    s += __shfl_down(s, off, 64);
  if ((tid & 63) == 0) red[tid >> 6] = s;
  __syncthreads();
  if (tid == 0)
    out[0] = (red[0] + red[1] + red[2] + red[3]) *
             (1.0f / (float)((size_t)NIMG * H * W));
}

extern "C" void kernel_launch(void* const* d_in, const int* in_sizes, int n_in,
                              void* d_out, int out_size, void* d_ws, size_t ws_size,
                              hipStream_t stream) {
  const float* I = (const float*)d_in[0];
  const float* J = (const float*)d_in[1];
  float* out     = (float*)d_out;
  float* partial = (float*)d_ws;            // 4096 * 4 B = 16 KB

  hipLaunchKernelGGL(ncc_main, dim3(NBLK), dim3(256), 0, stream, I, J, partial);
  hipLaunchKernelGGL(ncc_reduce, dim3(1), dim3(256), 0, stream, partial, out);
}

// Round 2
// 110.090 us; speedup vs baseline: 5.2153x; 5.2153x over previous
//
#include <hip/hip_runtime.h>

#define H 1024
#define W 1024
#define NIMG 8
#define CPT 4                   // columns per thread
#define TH 8                    // output rows per wave-tile
#define NBX 4                   // x-quadrants: 64 lanes * 4 cols * 4 = 1024
#define WPB 4                   // waves per block, stacked in y
#define NBY (H / (TH * WPB))    // 32
#define NBLK (NBX * NBY * NIMG) // 1024 blocks = 4 blocks/CU = 16 waves/CU
#define NWAVES (NBLK * WPB)     // 4096
#define EPS 1e-5f

struct RS { float I[CPT], J[CPT], II[CPT], JJ[CPT], IJ[CPT]; };

// Horizontal 9-box rowsums for 4 consecutive output columns [X, X+4),
// from 12 raw px per image (aligned float4 loads, edge-guarded).
// Loads are all issued up-front; straight-line, fully register-resident.
__device__ __forceinline__ void row_rs(const float* __restrict__ Irow,
                                       const float* __restrict__ Jrow,
                                       int X, bool okL, bool okR, RS& o) {
  float a[12], b[12];
  { float4 q = *reinterpret_cast<const float4*>(Irow + X);
    a[4]=q.x; a[5]=q.y; a[6]=q.z; a[7]=q.w;
    float4 p = *reinterpret_cast<const float4*>(Jrow + X);
    b[4]=p.x; b[5]=p.y; b[6]=p.z; b[7]=p.w; }
  if (okL) {
    float4 q = *reinterpret_cast<const float4*>(Irow + X - 4);
    a[0]=q.x; a[1]=q.y; a[2]=q.z; a[3]=q.w;
    float4 p = *reinterpret_cast<const float4*>(Jrow + X - 4);
    b[0]=p.x; b[1]=p.y; b[2]=p.z; b[3]=p.w;
  } else { a[0]=a[1]=a[2]=a[3]=0.f; b[0]=b[1]=b[2]=b[3]=0.f; }
  if (okR) {
    float4 q = *reinterpret_cast<const float4*>(Irow + X + 4);
    a[8]=q.x; a[9]=q.y; a[10]=q.z; a[11]=q.w;
    float4 p = *reinterpret_cast<const float4*>(Jrow + X + 4);
    b[8]=p.x; b[9]=p.y; b[10]=p.z; b[11]=p.w;
  } else { a[8]=a[9]=a[10]=a[11]=0.f; b[8]=b[9]=b[10]=b[11]=0.f; }

  float sI=0.f, sJ=0.f, sII=0.f, sJJ=0.f, sIJ=0.f;
  #pragma unroll
  for (int k = 0; k < 9; ++k) {
    sI += a[k]; sJ += b[k];
    sII = fmaf(a[k], a[k], sII);
    sJJ = fmaf(b[k], b[k], sJJ);
    sIJ = fmaf(a[k], b[k], sIJ);
  }
  o.I[0]=sI; o.J[0]=sJ; o.II[0]=sII; o.JJ[0]=sJJ; o.IJ[0]=sIJ;
  #pragma unroll
  for (int i = 1; i < CPT; ++i) {
    float an=a[i+8], al=a[i-1], bn=b[i+8], bl=b[i-1];
    sI += an - al;  sJ += bn - bl;
    sII = fmaf(-al, al, fmaf(an, an, sII));
    sJJ = fmaf(-bl, bl, fmaf(bn, bn, sJJ));
    sIJ = fmaf(-al, bl, fmaf(an, bn, sIJ));
    o.I[i]=sI; o.J[i]=sJ; o.II[i]=sII; o.JJ[i]=sJJ; o.IJ[i]=sIJ;
  }
}

// No LDS, no barriers: each wave independently walks a 256-col x 8-row tile,
// each thread a 4-col strip with vertical running window sums in registers.
// Leaving rows are re-loaded (L1/L2-hot) and recomputed instead of ring-kept.
// Latency hiding comes from TLP: 1024 blocks -> 4 blocks/CU -> 4 waves/SIMD.
__global__ __launch_bounds__(256, 4)
void ncc_main(const float* __restrict__ I, const float* __restrict__ J,
              float* __restrict__ partial) {
  const int tid  = threadIdx.x;
  const int lane = tid & 63, wv = tid >> 6;
  // XCD-bijective remap (NBLK = 1024 = 8 * 128): XCD k (= bid % 8) processes
  // contiguous tiles [k*128, (k+1)*128) == exactly image k -> vertical-halo
  // re-reads stay inside one XCD's L2 instead of cross-XCD HBM re-fetches.
  const int bid  = (int)blockIdx.x;
  const int tile = ((bid & 7) << 7) | (bid >> 3);
  const int bx   = tile & (NBX - 1);
  const int rest = tile / NBX;            // [0, 256)
  const int by   = rest & (NBY - 1);
  const int bz   = rest / NBY;            // image index
  const int X  = bx * 256 + lane * CPT;
  const int y0 = (by * WPB + wv) * TH;
  const bool okL = (X >= 4);
  const bool okR = (X + 8 <= W);
  const size_t img_off = (size_t)bz * H * W;
  const float* Ip = I + img_off;
  const float* Jp = J + img_off;

  float wI[CPT], wJ[CPT], wII[CPT], wJJ[CPT], wIJ[CPT];
  #pragma unroll
  for (int i = 0; i < CPT; ++i) { wI[i]=wJ[i]=wII[i]=wJJ[i]=wIJ[i]=0.f; }
  float acc = 0.f;
  const float inv81 = 1.0f / 81.0f;

  // sgn=+1: add row r's rowsums into window; sgn=-1: subtract (leave)
  auto apply = [&](int r, float sgn) {
    if ((unsigned)r < (unsigned)H) {
      RS o;
      row_rs(Ip + (size_t)r * W, Jp + (size_t)r * W, X, okL, okR, o);
      #pragma unroll
      for (int i = 0; i < CPT; ++i) {
        wI[i]  = fmaf(sgn, o.I[i],  wI[i]);
        wJ[i]  = fmaf(sgn, o.J[i],  wJ[i]);
        wII[i] = fmaf(sgn, o.II[i], wII[i]);
        wJJ[i] = fmaf(sgn, o.JJ[i], wJJ[i]);
        wIJ[i] = fmaf(sgn, o.IJ[i], wIJ[i]);
      }
    }
  };
  auto emit = [&]() {
    #pragma unroll
    for (int i = 0; i < CPT; ++i) {
      float cross = fmaf(-(wI[i] * wJ[i]), inv81, wIJ[i]);
      float Iv    = fmaf(-(wI[i] * wI[i]), inv81, wII[i]);
      float Jv    = fmaf(-(wJ[i] * wJ[i]), inv81, wJJ[i]);
      acc = fmaf(cross * cross,
                 __builtin_amdgcn_rcpf(fmaf(Iv, Jv, EPS)), acc);
    }
  };

  // warm-up: rows y0-4 .. y0+3
  for (int k = 0; k < 8; ++k) apply(y0 - 4 + k, 1.0f);
  // first output row: add y0+4, window = rows y0-4..y0+4
  apply(y0 + 4, 1.0f);
  emit();
  // steady state: add r, drop r-9, emit y=r-4
  for (int k = 0; k < TH - 1; ++k) {
    apply(y0 + 5 + k, 1.0f);
    apply(y0 - 4 + k, -1.0f);
    emit();
  }

  // wave reduction -> one partial per wave (no LDS, no barrier)
  #pragma unroll
  for (int off = 32; off > 0; off >>= 1)
    acc += __shfl_down(acc, off, 64);
  if (lane == 0)
    partial[tile * WPB + wv] = acc;
}

__global__ __launch_bounds__(256)
void ncc_reduce(const float* __restrict__ partial, float* __restrict__ out) {
  __shared__ float red[4];
  const int tid = threadIdx.x;
  const float4* p4 = reinterpret_cast<const float4*>(partial);
  float s = 0.f;
  #pragma unroll
  for (int i = tid; i < NWAVES / 4; i += 256) {
    float4 v = p4[i];
    s += (v.x + v.y) + (v.z + v.w);
  }
  #pragma unroll
  for (int off = 32; off > 0; off >>= 1)
    s += __shfl_down(s, off, 64);
  if ((tid & 63) == 0) red[tid >> 6] = s;
  __syncthreads();
  if (tid == 0)
    out[0] = (red[0] + red[1] + red[2] + red[3]) *
             (1.0f / (float)((size_t)NIMG * H * W));
}

extern "C" void kernel_launch(void* const* d_in, const int* in_sizes, int n_in,
                              void* d_out, int out_size, void* d_ws, size_t ws_size,
                              hipStream_t stream) {
  const float* I = (const float*)d_in[0];
  const float* J = (const float*)d_in[1];
  float* out     = (float*)d_out;
  float* partial = (float*)d_ws;            // 4096 * 4 B = 16 KB

  hipLaunchKernelGGL(ncc_main, dim3(NBLK), dim3(256), 0, stream, I, J, partial);
  hipLaunchKernelGGL(ncc_reduce, dim3(1), dim3(256), 0, stream, partial, out);
}